// Round 3
// baseline (8897.807 us; speedup 1.0000x reference)
//
#include <hip/hip_runtime.h>
#include <stdint.h>

// Persistent producer-consumer 2-layer LSTM for MI355X, split-bf16 precision.
// Plain (non-cooperative) launch: 128 wgs co-resident on 256 CUs by capacity.
// 8 batch clusters (16 rows); per cluster: 8 hidden-slice wgs per layer.
// h carried fp32 in ws ring buffers (depth 8), exchanged via agent-scope
// atomics with monotonic arrival counters. Weights in VGPRs as bf16 hi+lo;
// gates = Whi*xhi + Whi*xlo + Wlo*xhi via mfma_f32_16x16x32_bf16 (fp32 acc).

#define AGENT_SCOPE __HIP_MEMORY_SCOPE_AGENT

typedef float f32x4 __attribute__((ext_vector_type(4)));
typedef short s16x8 __attribute__((ext_vector_type(8)));
typedef int   i32x4 __attribute__((ext_vector_type(4)));
typedef unsigned short u16;
typedef unsigned int u32;
typedef unsigned long long u64;

#define N_T 1024
#define RING 8

__device__ __forceinline__ u16 f2bf(float f) {
  u32 u = __float_as_uint(f);
  u += 0x7FFFu + ((u >> 16) & 1u);
  return (u16)(u >> 16);
}
__device__ __forceinline__ float bf2f(u16 s) {
  return __uint_as_float(((u32)s) << 16);
}
__device__ __forceinline__ void split_bf(float v, u16& hi, u16& lo) {
  hi = f2bf(v);
  lo = f2bf(v - bf2f(hi));   // v - bf2f(hi) is exact in fp32
}
__device__ __forceinline__ float sigm(float v) { return 1.0f / (1.0f + __expf(-v)); }

__device__ __forceinline__ void spin_until(int* p, int target) {
  while (__hip_atomic_load(p, __ATOMIC_RELAXED, AGENT_SCOPE) != target)
    __builtin_amdgcn_s_sleep(1);
  __builtin_amdgcn_fence(__ATOMIC_ACQUIRE, "agent");
}

// pack 8 fp32 into 16B hi-bf16 + 16B lo-bf16 and store to (swizzled) LDS
__device__ __forceinline__ void stage8(char* dstH, char* dstL, int off, const float* v) {
  i32x4 H, L;
#pragma unroll
  for (int k = 0; k < 4; ++k) {
    u16 h0, l0, h1, l1;
    split_bf(v[2 * k], h0, l0);
    split_bf(v[2 * k + 1], h1, l1);
    H[k] = (int)((u32)h0 | ((u32)h1 << 16));
    L[k] = (int)((u32)l0 | ((u32)l1 << 16));
  }
  *(i32x4*)(dstH + off) = H;
  *(i32x4*)(dstL + off) = L;
}

// load 8 fp32 (granule g8) from a ring row via relaxed agent-scope u64 atomics
__device__ __forceinline__ void ld_ring8(const u64* row64, int g8, float* v) {
#pragma unroll
  for (int i = 0; i < 4; ++i) {
    u64 q = __hip_atomic_load((u64*)(row64 + g8 * 4 + i), __ATOMIC_RELAXED, AGENT_SCOPE);
    v[2 * i]     = __uint_as_float((u32)q);
    v[2 * i + 1] = __uint_as_float((u32)(q >> 32));
  }
}

template <int LAYER>
__device__ __forceinline__ void run_layer(
    int cl, int sl,
    const float* __restrict__ x,
    const float* __restrict__ Wxh, const float* __restrict__ bxh,
    const float* __restrict__ Whh, const float* __restrict__ bhh,
    const float* __restrict__ Wfc, const float* __restrict__ bfc,
    float* __restrict__ out,
    float* hr0f, float* hr1f, int* arrive0, int* arrive1, int* rd0, int* rd1,
    char* inbH, char* inbL, float* gatesS, float* biasS)
{
  constexpr int K   = LAYER ? 512 : 384;   // L0: [x(128); h(256)]  L1: [h0(256); h1(256)]
  constexpr int NKB = K / 32;
  constexpr int RB  = K * 2;               // LDS row bytes (bf16)

  const int tid  = threadIdx.x;
  const int wv   = tid >> 6;    // wave = gate index (i,f,g,o)
  const int lane = tid & 63;
  const int r15  = lane & 15;
  const int kg   = lane >> 4;

  // combined bias for this wg's 128 gate rows: biasS[g*32+u]
  if (tid < 128) {
    int g = tid >> 5, u = tid & 31;
    int row = g * 256 + sl * 32 + u;
    biasS[tid] = bxh[row] + bhh[row];
  }

  // ---- weight A-fragments in registers, split hi/lo. wave wv owns gate wv:
  // rows wv*256 + sl*32 + [0,32); two 16-row M tiles.
  s16x8 wAh[2][NKB], wAl[2][NKB];
#pragma unroll
  for (int mp = 0; mp < 2; ++mp) {
    const int grow = wv * 256 + sl * 32 + mp * 16 + r15;
#pragma unroll
    for (int kb = 0; kb < NKB; ++kb) {
      const int k0 = kb * 32 + kg * 8;
      const float* src;
      if (LAYER == 0) src = (k0 < 128) ? (Wxh + grow * 128 + k0) : (Whh + grow * 256 + (k0 - 128));
      else            src = (k0 < 256) ? (Wxh + grow * 256 + k0) : (Whh + grow * 256 + (k0 - 256));
      f32x4 a = *(const f32x4*)src;
      f32x4 b = *(const f32x4*)(src + 4);
      s16x8 vh, vl;
#pragma unroll
      for (int j = 0; j < 4; ++j) {
        u16 h, l;
        split_bf(a[j], h, l); vh[j] = (short)h; vl[j] = (short)l;
        split_bf(b[j], h, l); vh[4 + j] = (short)h; vl[4 + j] = (short)l;
      }
      wAh[mp][kb] = vh;
      wAl[mp][kb] = vl;
    }
  }

  const int bS   = tid >> 4;          // staging/update: batch row
  const int l16  = tid & 15;
  const int xorS = (bS & 7) << 4;     // 16B-granule XOR swizzle key (write side)
  float cpr0 = 0.f, cpr1 = 0.f;       // cell state: units sl*32+bS*2,+1 @ batch l16

  for (int t = 0; t < N_T; ++t) {
    // ---- L0: prefetch this thread's x granule into regs before the spin
    f32x4 xa, xb;
    if (LAYER == 0) {
      const float* xp = x + (((size_t)(cl * 16 + bS)) * N_T + t) * 128 + l16 * 8;
      xa = *(const f32x4*)xp;
      xb = *(const f32x4*)(xp + 4);
    }

    // ---- dependency + ring back-pressure waits (thread 0 only)
    if (tid == 0) {
      if (LAYER == 0) {
        if (t > 0)     spin_until(&arrive0[(t - 1) * 8 + cl], 8);
        if (t >= RING) spin_until(&rd0[(t - RING) * 8 + cl], 16);
      } else {
        spin_until(&arrive0[t * 8 + cl], 8);
        if (t > 0)     spin_until(&arrive1[(t - 1) * 8 + cl], 8);
        if (t >= RING) spin_until(&rd1[(t - RING) * 8 + cl], 8);
      }
    }
    __syncthreads();

    // ---- stage inputs (hi/lo bf16) into swizzled LDS rows [batch][K]
    char* rH = inbH + bS * RB;
    char* rL = inbL + bS * RB;
    if (LAYER == 0) {
      float v[8] = {xa[0], xa[1], xa[2], xa[3], xb[0], xb[1], xb[2], xb[3]};
      stage8(rH, rL, (l16 * 16) ^ xorS, v);
      const u64* hrow = (const u64*)(hr0f + ((size_t)(((t - 1) & (RING - 1)) * 8 + cl) * 16 + bS) * 256);
#pragma unroll
      for (int gg = 0; gg < 2; ++gg) {
        float v2[8];
        ld_ring8(hrow, l16 + gg * 16, v2);
        const int g = 16 + l16 + gg * 16;
        stage8(rH, rL, (g * 16) ^ xorS, v2);
      }
    } else {
      const u64* h0row = (const u64*)(hr0f + ((size_t)((t & (RING - 1)) * 8 + cl) * 16 + bS) * 256);
      const u64* h1row = (const u64*)(hr1f + ((size_t)(((t - 1) & (RING - 1)) * 8 + cl) * 16 + bS) * 256);
#pragma unroll
      for (int gg = 0; gg < 2; ++gg) {
        float v2[8];
        ld_ring8(h0row, l16 + gg * 16, v2);
        const int g = l16 + gg * 16;
        stage8(rH, rL, (g * 16) ^ xorS, v2);
      }
#pragma unroll
      for (int gg = 0; gg < 2; ++gg) {
        float v2[8];
        ld_ring8(h1row, l16 + gg * 16, v2);
        const int g = 32 + l16 + gg * 16;
        stage8(rH, rL, (g * 16) ^ xorS, v2);
      }
    }
    __syncthreads();

    // ---- signal "done reading" for ring back-pressure
    if (tid == 0) {
      if (LAYER == 0) {
        if (t > 0) __hip_atomic_fetch_add(&rd0[(t - 1) * 8 + cl], 1, __ATOMIC_RELEASE, AGENT_SCOPE);
      } else {
        __hip_atomic_fetch_add(&rd0[t * 8 + cl], 1, __ATOMIC_RELEASE, AGENT_SCOPE);
        if (t > 0) __hip_atomic_fetch_add(&rd1[(t - 1) * 8 + cl], 1, __ATOMIC_RELEASE, AGENT_SCOPE);
      }
    }

    // ---- MFMA: gates[128 rows x 16 batch] = Whi*xhi + Whi*xlo + Wlo*xhi
    f32x4 acc0 = {0.f, 0.f, 0.f, 0.f};
    f32x4 acc1 = {0.f, 0.f, 0.f, 0.f};
    const char* bbH = inbH + r15 * RB;    // B col = batch = lane&15
    const char* bbL = inbL + r15 * RB;
    const int bxor = (r15 & 7) << 4;
#pragma unroll
    for (int kb = 0; kb < NKB; ++kb) {
      const int off = (kb * 64 + kg * 16) ^ bxor;
      s16x8 bH = __builtin_bit_cast(s16x8, *(const i32x4*)(bbH + off));
      s16x8 bL = __builtin_bit_cast(s16x8, *(const i32x4*)(bbL + off));
      acc0 = __builtin_amdgcn_mfma_f32_16x16x32_bf16(wAh[0][kb], bH, acc0, 0, 0, 0);
      acc1 = __builtin_amdgcn_mfma_f32_16x16x32_bf16(wAh[1][kb], bH, acc1, 0, 0, 0);
      acc0 = __builtin_amdgcn_mfma_f32_16x16x32_bf16(wAh[0][kb], bL, acc0, 0, 0, 0);
      acc1 = __builtin_amdgcn_mfma_f32_16x16x32_bf16(wAh[1][kb], bL, acc1, 0, 0, 0);
      acc0 = __builtin_amdgcn_mfma_f32_16x16x32_bf16(wAl[0][kb], bH, acc0, 0, 0, 0);
      acc1 = __builtin_amdgcn_mfma_f32_16x16x32_bf16(wAl[1][kb], bH, acc1, 0, 0, 0);
    }
    // C/D: col = lane&15 (batch), row = (lane>>4)*4 + r
#pragma unroll
    for (int r = 0; r < 4; ++r) {
      gatesS[(wv * 32 + kg * 4 + r) * 17 + r15]      = acc0[r];
      gatesS[(wv * 32 + 16 + kg * 4 + r) * 17 + r15] = acc1[r];
    }
    __syncthreads();

    // ---- elementwise cell update: thread owns units sl*32+(2*bS,2*bS+1) @ batch l16
    {
      float hv0 = 0.f, hv1 = 0.f;
#pragma unroll
      for (int j = 0; j < 2; ++j) {
        const int u = bS * 2 + j;
        float pi = gatesS[(0 * 32 + u) * 17 + l16] + biasS[u];
        float pf = gatesS[(1 * 32 + u) * 17 + l16] + biasS[32 + u];
        float pg = gatesS[(2 * 32 + u) * 17 + l16] + biasS[64 + u];
        float po = gatesS[(3 * 32 + u) * 17 + l16] + biasS[96 + u];
        float ig = sigm(pi), fg = sigm(pf);
        float gg = tanhf(pg), og = sigm(po);
        float c = (j == 0 ? cpr0 : cpr1) * fg + ig * gg;
        if (j == 0) cpr0 = c; else cpr1 = c;
        float h = og * tanhf(c);
        if (j == 0) hv0 = h; else hv1 = h;
      }
      float* hOut = (LAYER ? hr1f : hr0f)
                  + ((size_t)((t & (RING - 1)) * 8 + cl) * 16 + l16) * 256
                  + sl * 32 + bS * 2;
      u64 pk = ((u64)__float_as_uint(hv1) << 32) | (u64)__float_as_uint(hv0);
      __hip_atomic_store((u64*)hOut, pk, __ATOMIC_RELAXED, AGENT_SCOPE);
    }
    __syncthreads();   // compiler drains vmcnt at barrier: all h stores visible
    if (tid == 0) {
      int* arr = (LAYER ? arrive1 : arrive0);
      __hip_atomic_fetch_add(&arr[t * 8 + cl], 1, __ATOMIC_RELEASE, AGENT_SCOPE);
    }
  }

  // ---- final FC on h1[T-1] (fp32): one wg per cluster (L1, slice 0)
  if (LAYER == 1 && sl == 0) {
    if (tid == 0) spin_until(&arrive1[1023 * 8 + cl], 8);
    __syncthreads();
    if (tid < 160) {
      const int b = tid / 10, oo = tid % 10;
      const u64* hp = (const u64*)(hr1f + ((size_t)((1023 & (RING - 1)) * 8 + cl) * 16 + b) * 256);
      float sum = bfc[oo];
      for (int u2 = 0; u2 < 128; ++u2) {
        u64 q = __hip_atomic_load((u64*)(hp + u2), __ATOMIC_RELAXED, AGENT_SCOPE);
        sum += __uint_as_float((u32)q)         * Wfc[oo * 256 + 2 * u2]
             + __uint_as_float((u32)(q >> 32)) * Wfc[oo * 256 + 2 * u2 + 1];
      }
      out[(cl * 16 + b) * 10 + oo] = sum;
    }
  }
}

__launch_bounds__(256, 1)
__global__ void lstm_kernel(const float* __restrict__ x,
    const float* __restrict__ Wxh0, const float* __restrict__ bxh0,
    const float* __restrict__ Whh0, const float* __restrict__ bhh0,
    const float* __restrict__ Wxh1, const float* __restrict__ bxh1,
    const float* __restrict__ Whh1, const float* __restrict__ bhh1,
    const float* __restrict__ Wfc, const float* __restrict__ bfc,
    float* __restrict__ out, char* __restrict__ ws)
{
  __shared__ __align__(16) char inbH[16 * 1024];
  __shared__ __align__(16) char inbL[16 * 1024];
  __shared__ float gatesS[4 * 32 * 17];
  __shared__ float biasS[128];

  // ws layout: hr0f 1MB | hr1f 1MB | flags 128KB   (total ~2.13MB)
  float* hr0f = (float*)ws;                    // [8][8][16][256] fp32
  float* hr1f = (float*)(ws + (1u << 20));
  int* arrive0 = (int*)(ws + (2u << 20));      // [1024][8] each
  int* arrive1 = arrive0 + N_T * 8;
  int* rd0 = arrive1 + N_T * 8;
  int* rd1 = rd0 + N_T * 8;

  const int bid = blockIdx.x;
  const int cl    = bid & 7;         // cluster -> XCD (round-robin dispatch)
  const int layer = (bid >> 3) & 1;  // 0/1
  const int sl    = bid >> 4;        // hidden slice 0..7

  if (layer == 0)
    run_layer<0>(cl, sl, x, Wxh0, bxh0, Whh0, bhh0, Wfc, bfc, out,
                 hr0f, hr1f, arrive0, arrive1, rd0, rd1, inbH, inbL, gatesS, biasS);
  else
    run_layer<1>(cl, sl, x, Wxh1, bxh1, Whh1, bhh1, Wfc, bfc, out,
                 hr0f, hr1f, arrive0, arrive1, rd0, rd1, inbH, inbL, gatesS, biasS);
}

extern "C" void kernel_launch(void* const* d_in, const int* in_sizes, int n_in,
                              void* d_out, int out_size, void* d_ws, size_t ws_size,
                              hipStream_t stream) {
  const float* x    = (const float*)d_in[0];
  const float* Wxh0 = (const float*)d_in[1];
  const float* bxh0 = (const float*)d_in[2];
  const float* Whh0 = (const float*)d_in[3];
  const float* bhh0 = (const float*)d_in[4];
  const float* Wxh1 = (const float*)d_in[5];
  const float* bxh1 = (const float*)d_in[6];
  const float* Whh1 = (const float*)d_in[7];
  const float* bhh1 = (const float*)d_in[8];
  const float* Wfc  = (const float*)d_in[9];
  const float* bfc  = (const float*)d_in[10];
  float* out = (float*)d_out;
  char* ws = (char*)d_ws;

  // zero rings + flags (harness poisons ws with 0xAA before every launch)
  size_t zero_bytes = (size_t)(2u << 20) + (size_t)4 * N_T * 8 * sizeof(int);
  hipMemsetAsync(d_ws, 0, zero_bytes, stream);

  lstm_kernel<<<dim3(128), dim3(256), 0, stream>>>(
      x, Wxh0, bxh0, Whh0, bhh0, Wxh1, bxh1, Whh1, bhh1, Wfc, bfc, out, ws);
}

// Round 4
// 7584.578 us; speedup vs baseline: 1.1731x; 1.1731x over previous
//
#include <hip/hip_runtime.h>
#include <stdint.h>

// Persistent producer-consumer 2-layer LSTM for MI355X, split-bf16 precision.
// 8 batch clusters (16 rows); per cluster: 8 hidden-slice wgs per layer.
// h carried as PRE-SPLIT bf16 hi/lo planes in ws ring buffers (depth 8),
// layout [slot][cl][sl][16][32] so each wg writes its own line-aligned 1KB
// block (no cross-XCD false sharing). Handoff: normal coalesced loads/stores
// + agent-scope release-add / relaxed-spin + acquire-fence.
// Weights in VGPRs/AGPRs as bf16 hi+lo; gates = Whi*xhi + Whi*xlo + Wlo*xhi
// via mfma_f32_16x16x32_bf16 (fp32 accum). Cell state fp32 in registers.

#define AGENT_SCOPE __HIP_MEMORY_SCOPE_AGENT

typedef float f32x4 __attribute__((ext_vector_type(4)));
typedef short s16x8 __attribute__((ext_vector_type(8)));
typedef int   i32x4 __attribute__((ext_vector_type(4)));
typedef unsigned short u16;
typedef unsigned int u32;
typedef unsigned long long u64;

#define N_T 1024
#define RING 8

__device__ __forceinline__ u16 f2bf(float f) {
  u32 u = __float_as_uint(f);
  u += 0x7FFFu + ((u >> 16) & 1u);
  return (u16)(u >> 16);
}
__device__ __forceinline__ float bf2f(u16 s) {
  return __uint_as_float(((u32)s) << 16);
}
__device__ __forceinline__ void split_bf(float v, u16& hi, u16& lo) {
  hi = f2bf(v);
  lo = f2bf(v - bf2f(hi));   // v - bf2f(hi) exact in fp32
}
__device__ __forceinline__ float sigm(float v) { return 1.0f / (1.0f + __expf(-v)); }

__device__ __forceinline__ void spin(int* p, int target) {
  while (__hip_atomic_load(p, __ATOMIC_RELAXED, AGENT_SCOPE) != target) { }
}

template <int LAYER>
__device__ __forceinline__ void run_layer(
    int cl, int sl,
    const float* __restrict__ x,
    const float* __restrict__ Wxh, const float* __restrict__ bxh,
    const float* __restrict__ Whh, const float* __restrict__ bhh,
    const float* __restrict__ Wfc, const float* __restrict__ bfc,
    float* __restrict__ out,
    u16* r0h, u16* r0l, u16* r1h, u16* r1l,
    int* arrive0, int* arrive1, int* rd0, int* rd1,
    char* inbH, char* inbL, float* gatesS, float* biasS)
{
  constexpr int K   = LAYER ? 512 : 384;   // L0: [x(128); h(256)]  L1: [h0(256); h1(256)]
  constexpr int NKB = K / 32;
  constexpr int RB  = K * 2;               // LDS row bytes (bf16)

  const int tid  = threadIdx.x;
  const int wv   = tid >> 6;    // wave = gate index (i,f,g,o)
  const int lane = tid & 63;
  const int r15  = lane & 15;
  const int kg   = lane >> 4;

  // combined bias for this wg's 128 gate rows: biasS[g*32+u]
  if (tid < 128) {
    int g = tid >> 5, u = tid & 31;
    int row = g * 256 + sl * 32 + u;
    biasS[tid] = bxh[row] + bhh[row];
  }

  // ---- weight A-fragments in registers, split hi/lo. wave wv owns gate wv:
  // rows wv*256 + sl*32 + [0,32); two 16-row M tiles.
  s16x8 wAh[2][NKB], wAl[2][NKB];
#pragma unroll
  for (int mp = 0; mp < 2; ++mp) {
    const int grow = wv * 256 + sl * 32 + mp * 16 + r15;
#pragma unroll
    for (int kb = 0; kb < NKB; ++kb) {
      const int k0 = kb * 32 + kg * 8;
      const float* src;
      if (LAYER == 0) src = (k0 < 128) ? (Wxh + grow * 128 + k0) : (Whh + grow * 256 + (k0 - 128));
      else            src = (k0 < 256) ? (Wxh + grow * 256 + k0) : (Whh + grow * 256 + (k0 - 256));
      f32x4 a = *(const f32x4*)src;
      f32x4 b = *(const f32x4*)(src + 4);
      s16x8 vh, vl;
#pragma unroll
      for (int j = 0; j < 4; ++j) {
        u16 h, l;
        split_bf(a[j], h, l); vh[j] = (short)h; vl[j] = (short)l;
        split_bf(b[j], h, l); vh[4 + j] = (short)h; vl[4 + j] = (short)l;
      }
      wAh[mp][kb] = vh;
      wAl[mp][kb] = vl;
    }
  }

  float cpr0 = 0.f, cpr1 = 0.f;   // cell state: units sl*32 + (tid&15)*2,+1 @ batch tid>>4

  for (int t = 0; t < N_T; ++t) {
    // ---- L0: prefetch + pre-split this thread's x chunks before the spin
    u64 xHi[2], xLo[2];
    int xB[2], xO[2];
    if (LAYER == 0) {
#pragma unroll
      for (int i = 0; i < 2; ++i) {
        const int c = i * 256 + tid, b = c >> 5, u4 = c & 31;
        const float* p = x + ((size_t)(cl * 16 + b) * N_T + t) * 128 + u4 * 4;
        f32x4 v = *(const f32x4*)p;
        u16 h0, l0, h1, l1, h2, l2, h3, l3;
        split_bf(v[0], h0, l0); split_bf(v[1], h1, l1);
        split_bf(v[2], h2, l2); split_bf(v[3], h3, l3);
        xHi[i] = (u64)((u32)h0 | ((u32)h1 << 16)) | ((u64)((u32)h2 | ((u32)h3 << 16)) << 32);
        xLo[i] = (u64)((u32)l0 | ((u32)l1 << 16)) | ((u64)((u32)l2 | ((u32)l3 << 16)) << 32);
        xB[i] = b; xO[i] = u4 * 8;
      }
    }

    if (LAYER == 0) {
      if (tid == 0) {
        if (t > 0)     spin(&arrive0[(t - 1) * 8 + cl], 8);
        if (t >= RING) spin(&rd0[(t - RING) * 8 + cl], 16);
        __builtin_amdgcn_fence(__ATOMIC_ACQUIRE, "agent");
      }
      __syncthreads();
      // x from regs
#pragma unroll
      for (int i = 0; i < 2; ++i) {
        const int b = xB[i], off = xO[i] ^ ((b & 7) << 4);
        *(u64*)(inbH + b * RB + off) = xHi[i];
        *(u64*)(inbL + b * RB + off) = xLo[i];
      }
      // h0[t-1] planes -> LDS k=[128,384)
      {
        const size_t sb = (size_t)(((t - 1) & (RING - 1)) * 8 + cl) * 4096;
#pragma unroll
        for (int i = 0; i < 2; ++i) {
          const int c = i * 256 + tid, u8 = c & 3, b = (c >> 2) & 15, s2 = c >> 6;
          const int ro = (s2 * 16 + b) * 32 + u8 * 8;       // ring elements
          i32x4 H = *(const i32x4*)(r0h + sb + ro);
          i32x4 L = *(const i32x4*)(r0l + sb + ro);
          const int off = (256 + s2 * 64 + u8 * 16) ^ ((b & 7) << 4);
          *(i32x4*)(inbH + b * RB + off) = H;
          *(i32x4*)(inbL + b * RB + off) = L;
        }
      }
      __syncthreads();
      if (tid == 0 && t > 0)
        __hip_atomic_fetch_add(&rd0[(t - 1) * 8 + cl], 1, __ATOMIC_RELEASE, AGENT_SCOPE);
    } else {
      // phase 1: own h1[t-1] (usually already available)
      if (tid == 0) {
        if (t > 0)     spin(&arrive1[(t - 1) * 8 + cl], 8);
        if (t >= RING) spin(&rd1[(t - RING) * 8 + cl], 8);
        __builtin_amdgcn_fence(__ATOMIC_ACQUIRE, "agent");
      }
      __syncthreads();
      {
        const size_t sb = (size_t)(((t - 1) & (RING - 1)) * 8 + cl) * 4096;
#pragma unroll
        for (int i = 0; i < 2; ++i) {
          const int c = i * 256 + tid, u8 = c & 3, b = (c >> 2) & 15, s2 = c >> 6;
          const int ro = (s2 * 16 + b) * 32 + u8 * 8;
          i32x4 H = *(const i32x4*)(r1h + sb + ro);
          i32x4 L = *(const i32x4*)(r1l + sb + ro);
          const int off = (512 + s2 * 64 + u8 * 16) ^ ((b & 7) << 4);
          *(i32x4*)(inbH + b * RB + off) = H;
          *(i32x4*)(inbL + b * RB + off) = L;
        }
      }
      // phase 2: fresh h0[t]
      if (tid == 0) {
        spin(&arrive0[t * 8 + cl], 8);
        __builtin_amdgcn_fence(__ATOMIC_ACQUIRE, "agent");
      }
      __syncthreads();
      {
        const size_t sb = (size_t)((t & (RING - 1)) * 8 + cl) * 4096;
#pragma unroll
        for (int i = 0; i < 2; ++i) {
          const int c = i * 256 + tid, u8 = c & 3, b = (c >> 2) & 15, s2 = c >> 6;
          const int ro = (s2 * 16 + b) * 32 + u8 * 8;
          i32x4 H = *(const i32x4*)(r0h + sb + ro);
          i32x4 L = *(const i32x4*)(r0l + sb + ro);
          const int off = (s2 * 64 + u8 * 16) ^ ((b & 7) << 4);
          *(i32x4*)(inbH + b * RB + off) = H;
          *(i32x4*)(inbL + b * RB + off) = L;
        }
      }
      __syncthreads();
      if (tid == 0) {
        __hip_atomic_fetch_add(&rd0[t * 8 + cl], 1, __ATOMIC_RELEASE, AGENT_SCOPE);
        if (t > 0)
          __hip_atomic_fetch_add(&rd1[(t - 1) * 8 + cl], 1, __ATOMIC_RELEASE, AGENT_SCOPE);
      }
    }

    // ---- MFMA: gates[128 rows x 16 batch] = Whi*xhi + Whi*xlo + Wlo*xhi
    f32x4 acc0 = {0.f, 0.f, 0.f, 0.f};
    f32x4 acc1 = {0.f, 0.f, 0.f, 0.f};
    const char* bbH = inbH + r15 * RB;    // B col = batch = lane&15
    const char* bbL = inbL + r15 * RB;
    const int bxor = (r15 & 7) << 4;
#pragma unroll
    for (int kb = 0; kb < NKB; ++kb) {
      const int off = (kb * 64 + kg * 16) ^ bxor;
      s16x8 bH = __builtin_bit_cast(s16x8, *(const i32x4*)(bbH + off));
      s16x8 bL = __builtin_bit_cast(s16x8, *(const i32x4*)(bbL + off));
      acc0 = __builtin_amdgcn_mfma_f32_16x16x32_bf16(wAh[0][kb], bH, acc0, 0, 0, 0);
      acc1 = __builtin_amdgcn_mfma_f32_16x16x32_bf16(wAh[1][kb], bH, acc1, 0, 0, 0);
      acc0 = __builtin_amdgcn_mfma_f32_16x16x32_bf16(wAh[0][kb], bL, acc0, 0, 0, 0);
      acc1 = __builtin_amdgcn_mfma_f32_16x16x32_bf16(wAh[1][kb], bL, acc1, 0, 0, 0);
      acc0 = __builtin_amdgcn_mfma_f32_16x16x32_bf16(wAl[0][kb], bH, acc0, 0, 0, 0);
      acc1 = __builtin_amdgcn_mfma_f32_16x16x32_bf16(wAl[1][kb], bH, acc1, 0, 0, 0);
    }
    // C/D: col = lane&15 (batch), row = (lane>>4)*4 + r
#pragma unroll
    for (int r = 0; r < 4; ++r) {
      gatesS[(wv * 32 + kg * 4 + r) * 17 + r15]      = acc0[r];
      gatesS[(wv * 32 + 16 + kg * 4 + r) * 17 + r15] = acc1[r];
    }
    __syncthreads();

    // ---- elementwise: thread owns units sl*32 + (2*up, 2*up+1) @ batch b
    {
      const int up = tid & 15, b = tid >> 4;
      float hv[2];
#pragma unroll
      for (int j = 0; j < 2; ++j) {
        const int u = up * 2 + j;
        float pi = gatesS[(0 * 32 + u) * 17 + b] + biasS[u];
        float pf = gatesS[(1 * 32 + u) * 17 + b] + biasS[32 + u];
        float pg = gatesS[(2 * 32 + u) * 17 + b] + biasS[64 + u];
        float po = gatesS[(3 * 32 + u) * 17 + b] + biasS[96 + u];
        float ig = sigm(pi), fg = sigm(pf);
        float gg = tanhf(pg), og = sigm(po);
        float c = (j == 0 ? cpr0 : cpr1) * fg + ig * gg;
        if (j == 0) cpr0 = c; else cpr1 = c;
        hv[j] = og * tanhf(c);
      }
      u16 h0, l0, h1, l1;
      split_bf(hv[0], h0, l0);
      split_bf(hv[1], h1, l1);
      const size_t eb = (size_t)((t & (RING - 1)) * 8 + cl) * 4096
                      + (size_t)(sl * 16 + b) * 32 + up * 2;
      *(u32*)((LAYER ? r1h : r0h) + eb) = (u32)h0 | ((u32)h1 << 16);
      *(u32*)((LAYER ? r1l : r0l) + eb) = (u32)l0 | ((u32)l1 << 16);
    }
    __syncthreads();   // all stores in L2 (vmcnt drained) before the release-add
    if (tid == 0) {
      int* arr = (LAYER ? arrive1 : arrive0);
      __hip_atomic_fetch_add(&arr[t * 8 + cl], 1, __ATOMIC_RELEASE, AGENT_SCOPE);
    }
  }

  // ---- final FC on h1[T-1] = hi+lo: one wg per cluster (L1, slice 0)
  if (LAYER == 1 && sl == 0) {
    if (tid == 0) {
      spin(&arrive1[1023 * 8 + cl], 8);
      __builtin_amdgcn_fence(__ATOMIC_ACQUIRE, "agent");
    }
    __syncthreads();
    if (tid < 160) {
      const int b = tid / 10, oo = tid % 10;
      const size_t sb = (size_t)((1023 & (RING - 1)) * 8 + cl) * 4096;
      float sum = bfc[oo];
      for (int u2 = 0; u2 < 128; ++u2) {
        const int s2 = u2 >> 4, uu = (u2 & 15) * 2;
        const size_t ro = sb + (size_t)(s2 * 16 + b) * 32 + uu;
        u32 qh = *(const u32*)(r1h + ro);
        u32 ql = *(const u32*)(r1l + ro);
        float v0 = bf2f((u16)qh)         + bf2f((u16)ql);
        float v1 = bf2f((u16)(qh >> 16)) + bf2f((u16)(ql >> 16));
        sum += v0 * Wfc[oo * 256 + 2 * u2] + v1 * Wfc[oo * 256 + 2 * u2 + 1];
      }
      out[(cl * 16 + b) * 10 + oo] = sum;
    }
  }
}

__launch_bounds__(256, 1)
__global__ void lstm_kernel(const float* __restrict__ x,
    const float* __restrict__ Wxh0, const float* __restrict__ bxh0,
    const float* __restrict__ Whh0, const float* __restrict__ bhh0,
    const float* __restrict__ Wxh1, const float* __restrict__ bxh1,
    const float* __restrict__ Whh1, const float* __restrict__ bhh1,
    const float* __restrict__ Wfc, const float* __restrict__ bfc,
    float* __restrict__ out, char* __restrict__ ws)
{
  __shared__ __align__(16) char inbH[16 * 1024];
  __shared__ __align__(16) char inbL[16 * 1024];
  __shared__ float gatesS[4 * 32 * 17];
  __shared__ float biasS[128];

  // ws: 4 bf16 planes [RING][8cl][8sl][16b][32u] of 512KB each, flags at 2MB
  u16* r0h = (u16*)ws;
  u16* r0l = (u16*)(ws + (512u << 10));
  u16* r1h = (u16*)(ws + (1024u << 10));
  u16* r1l = (u16*)(ws + (1536u << 10));
  int* arrive0 = (int*)(ws + (2048u << 10));   // [1024][8] each
  int* arrive1 = arrive0 + N_T * 8;
  int* rd0 = arrive1 + N_T * 8;
  int* rd1 = rd0 + N_T * 8;

  const int bid = blockIdx.x;
  const int cl    = bid & 7;         // cluster -> XCD (round-robin heuristic)
  const int layer = (bid >> 3) & 1;  // 0/1
  const int sl    = bid >> 4;        // hidden slice 0..7

  if (layer == 0)
    run_layer<0>(cl, sl, x, Wxh0, bxh0, Whh0, bhh0, Wfc, bfc, out,
                 r0h, r0l, r1h, r1l, arrive0, arrive1, rd0, rd1,
                 inbH, inbL, gatesS, biasS);
  else
    run_layer<1>(cl, sl, x, Wxh1, bxh1, Whh1, bhh1, Wfc, bfc, out,
                 r0h, r0l, r1h, r1l, arrive0, arrive1, rd0, rd1,
                 inbH, inbL, gatesS, biasS);
}

extern "C" void kernel_launch(void* const* d_in, const int* in_sizes, int n_in,
                              void* d_out, int out_size, void* d_ws, size_t ws_size,
                              hipStream_t stream) {
  const float* x    = (const float*)d_in[0];
  const float* Wxh0 = (const float*)d_in[1];
  const float* bxh0 = (const float*)d_in[2];
  const float* Whh0 = (const float*)d_in[3];
  const float* bhh0 = (const float*)d_in[4];
  const float* Wxh1 = (const float*)d_in[5];
  const float* bxh1 = (const float*)d_in[6];
  const float* Whh1 = (const float*)d_in[7];
  const float* bhh1 = (const float*)d_in[8];
  const float* Wfc  = (const float*)d_in[9];
  const float* bfc  = (const float*)d_in[10];
  float* out = (float*)d_out;
  char* ws = (char*)d_ws;

  // zero rings + flags (harness poisons ws with 0xAA before every launch)
  size_t zero_bytes = (size_t)(2048u << 10) + (size_t)4 * N_T * 8 * sizeof(int);
  hipMemsetAsync(d_ws, 0, zero_bytes, stream);

  lstm_kernel<<<dim3(128), dim3(256), 0, stream>>>(
      x, Wxh0, bxh0, Whh0, bhh0, Wxh1, bxh1, Whh1, bhh1, Wfc, bfc, out, ws);
}

// Round 5
// 4048.744 us; speedup vs baseline: 2.1977x; 1.8733x over previous
//
#include <hip/hip_runtime.h>
#include <stdint.h>

// Persistent producer-consumer 2-layer LSTM for MI355X, split-bf16 precision.
// 8 batch clusters (16 rows); per cluster: 8 hidden-slice wgs per layer.
// h carried as PRE-SPLIT bf16 hi/lo planes in ws ring buffers (depth 8).
// NO agent fences (they compile to full-L2 inv/writeback on gfx950).
// Instead: ring data moves via inline-asm sc0 sc1 (coherence-point) loads
// and stores; flags are relaxed agent atomics + sc0sc1 spin loads.
// Weights in registers as bf16 hi+lo; gates = Whi*xhi + Whi*xlo + Wlo*xhi
// via mfma_f32_16x16x32_bf16 (fp32 accum). Cell state fp32 in registers.

#define AGENT_SCOPE __HIP_MEMORY_SCOPE_AGENT

typedef float f32x4 __attribute__((ext_vector_type(4)));
typedef short s16x8 __attribute__((ext_vector_type(8)));
typedef int   i32x4 __attribute__((ext_vector_type(4)));
typedef unsigned short u16;
typedef unsigned int u32;
typedef unsigned long long u64;

#define N_T 1024
#define RING 8

__device__ __forceinline__ u16 f2bf(float f) {
  u32 u = __float_as_uint(f);
  u += 0x7FFFu + ((u >> 16) & 1u);
  return (u16)(u >> 16);
}
__device__ __forceinline__ float bf2f(u16 s) {
  return __uint_as_float(((u32)s) << 16);
}
__device__ __forceinline__ void split_bf(float v, u16& hi, u16& lo) {
  hi = f2bf(v);
  lo = f2bf(v - bf2f(hi));   // exact in fp32
}
__device__ __forceinline__ float sigm(float v) { return 1.0f / (1.0f + __expf(-v)); }

// ---- coherence-point (sc0 sc1) primitives: per-access coherent, no cache-wide ops
__device__ __forceinline__ void st_coh_u32(void* p, u32 v) {
  asm volatile("global_store_dword %0, %1, off sc0 sc1" :: "v"(p), "v"(v) : "memory");
}
__device__ __forceinline__ void ld_coh_4x16(const void* p0, const void* p1,
                                            const void* p2, const void* p3,
                                            i32x4& a, i32x4& b, i32x4& c, i32x4& d) {
  asm volatile(
      "global_load_dwordx4 %0, %4, off sc0 sc1\n\t"
      "global_load_dwordx4 %1, %5, off sc0 sc1\n\t"
      "global_load_dwordx4 %2, %6, off sc0 sc1\n\t"
      "global_load_dwordx4 %3, %7, off sc0 sc1\n\t"
      "s_waitcnt vmcnt(0)"
      : "=&v"(a), "=&v"(b), "=&v"(c), "=&v"(d)
      : "v"(p0), "v"(p1), "v"(p2), "v"(p3)
      : "memory");
}
__device__ __forceinline__ void spin1(const int* p, int tgt) {
  for (;;) {
    int a;
    asm volatile("global_load_dword %0, %1, off sc0 sc1\n\ts_waitcnt vmcnt(0)"
                 : "=&v"(a) : "v"(p) : "memory");
    if (a == tgt) return;
    __builtin_amdgcn_s_sleep(1);
  }
}
__device__ __forceinline__ void spin2(const int* p0, const int* p1, int t0, int t1) {
  for (;;) {
    int a, b;
    asm volatile(
        "global_load_dword %0, %2, off sc0 sc1\n\t"
        "global_load_dword %1, %3, off sc0 sc1\n\t"
        "s_waitcnt vmcnt(0)"
        : "=&v"(a), "=&v"(b) : "v"(p0), "v"(p1) : "memory");
    if (a == t0 && b == t1) return;
    __builtin_amdgcn_s_sleep(1);
  }
}

template <int LAYER>
__device__ __forceinline__ void run_layer(
    int cl, int sl,
    const float* __restrict__ x,
    const float* __restrict__ Wxh, const float* __restrict__ bxh,
    const float* __restrict__ Whh, const float* __restrict__ bhh,
    const float* __restrict__ Wfc, const float* __restrict__ bfc,
    float* __restrict__ out,
    u16* r0h, u16* r0l, u16* r1h, u16* r1l,
    int* arrive0, int* arrive1, int* rd0, int* rd1,
    char* inbH, char* inbL, float* gatesS, float* biasS)
{
  constexpr int K   = LAYER ? 512 : 384;   // L0: [x(128); h0(256)]  L1: [h0(256); h1(256)]
  constexpr int NKB = K / 32;
  constexpr int RB  = K * 2;               // LDS row bytes (bf16)

  const int tid  = threadIdx.x;
  const int wv   = tid >> 6;    // wave = gate index (i,f,g,o)
  const int lane = tid & 63;
  const int r15  = lane & 15;
  const int kg   = lane >> 4;

  if (tid < 128) {
    int g = tid >> 5, u = tid & 31;
    int row = g * 256 + sl * 32 + u;
    biasS[tid] = bxh[row] + bhh[row];
  }

  // ---- weight A-fragments in registers, split hi/lo
  s16x8 wAh[2][NKB], wAl[2][NKB];
#pragma unroll
  for (int mp = 0; mp < 2; ++mp) {
    const int grow = wv * 256 + sl * 32 + mp * 16 + r15;
#pragma unroll
    for (int kb = 0; kb < NKB; ++kb) {
      const int k0 = kb * 32 + kg * 8;
      const float* src;
      if (LAYER == 0) src = (k0 < 128) ? (Wxh + grow * 128 + k0) : (Whh + grow * 256 + (k0 - 128));
      else            src = (k0 < 256) ? (Wxh + grow * 256 + k0) : (Whh + grow * 256 + (k0 - 256));
      f32x4 a = *(const f32x4*)src;
      f32x4 b = *(const f32x4*)(src + 4);
      s16x8 vh, vl;
#pragma unroll
      for (int j = 0; j < 4; ++j) {
        u16 h, l;
        split_bf(a[j], h, l); vh[j] = (short)h; vl[j] = (short)l;
        split_bf(b[j], h, l); vh[4 + j] = (short)h; vl[4 + j] = (short)l;
      }
      wAh[mp][kb] = vh;
      wAl[mp][kb] = vl;
    }
  }

  float cpr0 = 0.f, cpr1 = 0.f;

  for (int t = 0; t < N_T; ++t) {
    // ---- L0: prefetch + pre-split this thread's x chunks before the spin
    u64 xHi[2], xLo[2];
    int xB[2], xO[2];
    if (LAYER == 0) {
#pragma unroll
      for (int i = 0; i < 2; ++i) {
        const int c = i * 256 + tid, b = c >> 5, u4 = c & 31;
        const float* p = x + ((size_t)(cl * 16 + b) * N_T + t) * 128 + u4 * 4;
        f32x4 v = *(const f32x4*)p;
        u16 h0, l0, h1, l1, h2, l2, h3, l3;
        split_bf(v[0], h0, l0); split_bf(v[1], h1, l1);
        split_bf(v[2], h2, l2); split_bf(v[3], h3, l3);
        xHi[i] = (u64)((u32)h0 | ((u32)h1 << 16)) | ((u64)((u32)h2 | ((u32)h3 << 16)) << 32);
        xLo[i] = (u64)((u32)l0 | ((u32)l1 << 16)) | ((u64)((u32)l2 | ((u32)l3 << 16)) << 32);
        xB[i] = b; xO[i] = u4 * 8;
      }
    }

    if (LAYER == 0) {
      // deps: arrive0[t-1]==8 ; back-pressure rd0[t-8]==8 (L1 read h0[t-8])
      if (tid == 0) {
        if (t >= RING)  spin2(&arrive0[(t - 1) * 8 + cl], &rd0[(t - RING) * 8 + cl], 8, 8);
        else if (t > 0) spin1(&arrive0[(t - 1) * 8 + cl], 8);
      }
      __syncthreads();
      // x from regs -> LDS
#pragma unroll
      for (int i = 0; i < 2; ++i) {
        const int b = xB[i], off = xO[i] ^ ((b & 7) << 4);
        *(u64*)(inbH + b * RB + off) = xHi[i];
        *(u64*)(inbL + b * RB + off) = xLo[i];
      }
      // h0[t-1] (slot zeros at t=0) -> LDS k=[128,384)
      {
        const size_t sb = (size_t)(((t - 1) & (RING - 1)) * 8 + cl) * 4096;
        const int c0 = tid,        u80 = c0 & 3, b0 = (c0 >> 2) & 15, s20 = c0 >> 6;
        const int c1 = 256 + tid,  u81 = c1 & 3, b1 = (c1 >> 2) & 15, s21 = c1 >> 6;
        const int ro0 = (s20 * 16 + b0) * 32 + u80 * 8;
        const int ro1 = (s21 * 16 + b1) * 32 + u81 * 8;
        i32x4 H0, L0v, H1, L1v;
        ld_coh_4x16(r0h + sb + ro0, r0l + sb + ro0, r0h + sb + ro1, r0l + sb + ro1,
                    H0, L0v, H1, L1v);
        const int off0 = (256 + s20 * 64 + u80 * 16) ^ ((b0 & 7) << 4);
        const int off1 = (256 + s21 * 64 + u81 * 16) ^ ((b1 & 7) << 4);
        *(i32x4*)(inbH + b0 * RB + off0) = H0;
        *(i32x4*)(inbL + b0 * RB + off0) = L0v;
        *(i32x4*)(inbH + b1 * RB + off1) = H1;
        *(i32x4*)(inbL + b1 * RB + off1) = L1v;
      }
      __syncthreads();
    } else {
      // phase 1: h1[t-1] ; back-pressure rd1[t-8]==8 (siblings read h1[t-8])
      if (tid == 0) {
        if (t >= RING)  spin2(&arrive1[(t - 1) * 8 + cl], &rd1[(t - RING) * 8 + cl], 8, 8);
        else if (t > 0) spin1(&arrive1[(t - 1) * 8 + cl], 8);
      }
      __syncthreads();
      {
        const size_t sb = (size_t)(((t - 1) & (RING - 1)) * 8 + cl) * 4096;
        const int c0 = tid,        u80 = c0 & 3, b0 = (c0 >> 2) & 15, s20 = c0 >> 6;
        const int c1 = 256 + tid,  u81 = c1 & 3, b1 = (c1 >> 2) & 15, s21 = c1 >> 6;
        const int ro0 = (s20 * 16 + b0) * 32 + u80 * 8;
        const int ro1 = (s21 * 16 + b1) * 32 + u81 * 8;
        i32x4 H0, L0v, H1, L1v;
        ld_coh_4x16(r1h + sb + ro0, r1l + sb + ro0, r1h + sb + ro1, r1l + sb + ro1,
                    H0, L0v, H1, L1v);
        const int off0 = (512 + s20 * 64 + u80 * 16) ^ ((b0 & 7) << 4);
        const int off1 = (512 + s21 * 64 + u81 * 16) ^ ((b1 & 7) << 4);
        *(i32x4*)(inbH + b0 * RB + off0) = H0;
        *(i32x4*)(inbL + b0 * RB + off0) = L0v;
        *(i32x4*)(inbH + b1 * RB + off1) = H1;
        *(i32x4*)(inbL + b1 * RB + off1) = L1v;
      }
      // phase 2: fresh h0[t]
      if (tid == 0) spin1(&arrive0[t * 8 + cl], 8);
      __syncthreads();   // all phase-1 ring reads complete (per-thread waitcnt) here
      if (tid == 0 && t > 0)
        __hip_atomic_fetch_add(&rd1[(t - 1) * 8 + cl], 1, __ATOMIC_RELAXED, AGENT_SCOPE);
      {
        const size_t sb = (size_t)((t & (RING - 1)) * 8 + cl) * 4096;
        const int c0 = tid,        u80 = c0 & 3, b0 = (c0 >> 2) & 15, s20 = c0 >> 6;
        const int c1 = 256 + tid,  u81 = c1 & 3, b1 = (c1 >> 2) & 15, s21 = c1 >> 6;
        const int ro0 = (s20 * 16 + b0) * 32 + u80 * 8;
        const int ro1 = (s21 * 16 + b1) * 32 + u81 * 8;
        i32x4 H0, L0v, H1, L1v;
        ld_coh_4x16(r0h + sb + ro0, r0l + sb + ro0, r0h + sb + ro1, r0l + sb + ro1,
                    H0, L0v, H1, L1v);
        const int off0 = (s20 * 64 + u80 * 16) ^ ((b0 & 7) << 4);
        const int off1 = (s21 * 64 + u81 * 16) ^ ((b1 & 7) << 4);
        *(i32x4*)(inbH + b0 * RB + off0) = H0;
        *(i32x4*)(inbL + b0 * RB + off0) = L0v;
        *(i32x4*)(inbH + b1 * RB + off1) = H1;
        *(i32x4*)(inbL + b1 * RB + off1) = L1v;
      }
      __syncthreads();
      if (tid == 0)
        __hip_atomic_fetch_add(&rd0[t * 8 + cl], 1, __ATOMIC_RELAXED, AGENT_SCOPE);
    }

    // ---- MFMA: gates[128 rows x 16 batch] = Whi*xhi + Whi*xlo + Wlo*xhi
    f32x4 acc0 = {0.f, 0.f, 0.f, 0.f};
    f32x4 acc1 = {0.f, 0.f, 0.f, 0.f};
    const char* bbH = inbH + r15 * RB;    // B col = batch = lane&15
    const char* bbL = inbL + r15 * RB;
    const int bxor = (r15 & 7) << 4;
#pragma unroll
    for (int kb = 0; kb < NKB; ++kb) {
      const int off = (kb * 64 + kg * 16) ^ bxor;
      s16x8 bH = __builtin_bit_cast(s16x8, *(const i32x4*)(bbH + off));
      s16x8 bL = __builtin_bit_cast(s16x8, *(const i32x4*)(bbL + off));
      acc0 = __builtin_amdgcn_mfma_f32_16x16x32_bf16(wAh[0][kb], bH, acc0, 0, 0, 0);
      acc1 = __builtin_amdgcn_mfma_f32_16x16x32_bf16(wAh[1][kb], bH, acc1, 0, 0, 0);
      acc0 = __builtin_amdgcn_mfma_f32_16x16x32_bf16(wAh[0][kb], bL, acc0, 0, 0, 0);
      acc1 = __builtin_amdgcn_mfma_f32_16x16x32_bf16(wAh[1][kb], bL, acc1, 0, 0, 0);
      acc0 = __builtin_amdgcn_mfma_f32_16x16x32_bf16(wAl[0][kb], bH, acc0, 0, 0, 0);
      acc1 = __builtin_amdgcn_mfma_f32_16x16x32_bf16(wAl[1][kb], bH, acc1, 0, 0, 0);
    }
#pragma unroll
    for (int r = 0; r < 4; ++r) {
      gatesS[(wv * 32 + kg * 4 + r) * 17 + r15]      = acc0[r];
      gatesS[(wv * 32 + 16 + kg * 4 + r) * 17 + r15] = acc1[r];
    }
    __syncthreads();

    // ---- elementwise: thread owns units sl*32 + (2*up, 2*up+1) @ batch b
    {
      const int up = tid & 15, b = tid >> 4;
      float hv[2];
#pragma unroll
      for (int j = 0; j < 2; ++j) {
        const int u = up * 2 + j;
        float pi = gatesS[(0 * 32 + u) * 17 + b] + biasS[u];
        float pf = gatesS[(1 * 32 + u) * 17 + b] + biasS[32 + u];
        float pg = gatesS[(2 * 32 + u) * 17 + b] + biasS[64 + u];
        float po = gatesS[(3 * 32 + u) * 17 + b] + biasS[96 + u];
        float ig = sigm(pi), fg = sigm(pf);
        float gg = tanhf(pg), og = sigm(po);
        float c = (j == 0 ? cpr0 : cpr1) * fg + ig * gg;
        if (j == 0) cpr0 = c; else cpr1 = c;
        hv[j] = og * tanhf(c);
      }
      u16 h0, l0, h1, l1;
      split_bf(hv[0], h0, l0);
      split_bf(hv[1], h1, l1);
      const size_t eb = (size_t)((t & (RING - 1)) * 8 + cl) * 4096
                      + (size_t)(sl * 16 + b) * 32 + up * 2;
      st_coh_u32((LAYER ? r1h : r0h) + eb, (u32)h0 | ((u32)h1 << 16));
      st_coh_u32((LAYER ? r1l : r0l) + eb, (u32)l0 | ((u32)l1 << 16));
    }
    asm volatile("s_waitcnt vmcnt(0)" ::: "memory");   // h stores at coherence point
    __syncthreads();
    if (tid == 0) {
      int* arr = (LAYER ? arrive1 : arrive0);
      __hip_atomic_fetch_add(&arr[t * 8 + cl], 1, __ATOMIC_RELAXED, AGENT_SCOPE);
    }
  }

  // ---- final FC on h1[T-1] = hi+lo: one wg per cluster (L1, slice 0)
  if (LAYER == 1 && sl == 0) {
    if (tid == 0) spin1(&arrive1[1023 * 8 + cl], 8);
    __syncthreads();
    // stage whole h1 slot (8KB hi + 8KB lo) into LDS via coherent loads
    {
      const size_t sb = (size_t)((1023 & (RING - 1)) * 8 + cl) * 4096;
      const u16* ph = r1h + sb + tid * 16;
      const u16* pl = r1l + sb + tid * 16;
      i32x4 H0, H1, L0v, L1v;
      ld_coh_4x16(ph, ph + 8, pl, pl + 8, H0, H1, L0v, L1v);
      *(i32x4*)(inbH + tid * 32)      = H0;
      *(i32x4*)(inbH + tid * 32 + 16) = H1;
      *(i32x4*)(inbL + tid * 32)      = L0v;
      *(i32x4*)(inbL + tid * 32 + 16) = L1v;
    }
    __syncthreads();
    if (tid < 160) {
      const int b = tid / 10, oo = tid % 10;
      const u16* fH = (const u16*)inbH;
      const u16* fL = (const u16*)inbL;
      float sum = bfc[oo];
      for (int u = 0; u < 256; ++u) {
        const int elem = ((u >> 5) * 16 + b) * 32 + (u & 31);
        float v = bf2f(fH[elem]) + bf2f(fL[elem]);
        sum += v * Wfc[oo * 256 + u];
      }
      out[(cl * 16 + b) * 10 + oo] = sum;
    }
  }
}

__launch_bounds__(256, 1)
__global__ void lstm_kernel(const float* __restrict__ x,
    const float* __restrict__ Wxh0, const float* __restrict__ bxh0,
    const float* __restrict__ Whh0, const float* __restrict__ bhh0,
    const float* __restrict__ Wxh1, const float* __restrict__ bxh1,
    const float* __restrict__ Whh1, const float* __restrict__ bhh1,
    const float* __restrict__ Wfc, const float* __restrict__ bfc,
    float* __restrict__ out, char* __restrict__ ws)
{
  __shared__ __align__(16) char inbH[16 * 1024];
  __shared__ __align__(16) char inbL[16 * 1024];
  __shared__ float gatesS[4 * 32 * 17];
  __shared__ float biasS[128];

  // ws: 4 bf16 planes [RING][8cl][8sl][16b][32u] of 512KB each, flags at 2MB
  u16* r0h = (u16*)ws;
  u16* r0l = (u16*)(ws + (512u << 10));
  u16* r1h = (u16*)(ws + (1024u << 10));
  u16* r1l = (u16*)(ws + (1536u << 10));
  int* arrive0 = (int*)(ws + (2048u << 10));   // [1024][8] each
  int* arrive1 = arrive0 + N_T * 8;
  int* rd0 = arrive1 + N_T * 8;
  int* rd1 = rd0 + N_T * 8;

  const int bid = blockIdx.x;
  const int cl    = bid & 7;         // cluster -> XCD (locality heuristic only)
  const int layer = (bid >> 3) & 1;  // 0/1
  const int sl    = bid >> 4;        // hidden slice 0..7

  if (layer == 0)
    run_layer<0>(cl, sl, x, Wxh0, bxh0, Whh0, bhh0, Wfc, bfc, out,
                 r0h, r0l, r1h, r1l, arrive0, arrive1, rd0, rd1,
                 inbH, inbL, gatesS, biasS);
  else
    run_layer<1>(cl, sl, x, Wxh1, bxh1, Whh1, bhh1, Wfc, bfc, out,
                 r0h, r0l, r1h, r1l, arrive0, arrive1, rd0, rd1,
                 inbH, inbL, gatesS, biasS);
}

extern "C" void kernel_launch(void* const* d_in, const int* in_sizes, int n_in,
                              void* d_out, int out_size, void* d_ws, size_t ws_size,
                              hipStream_t stream) {
  const float* x    = (const float*)d_in[0];
  const float* Wxh0 = (const float*)d_in[1];
  const float* bxh0 = (const float*)d_in[2];
  const float* Whh0 = (const float*)d_in[3];
  const float* bhh0 = (const float*)d_in[4];
  const float* Wxh1 = (const float*)d_in[5];
  const float* bxh1 = (const float*)d_in[6];
  const float* Whh1 = (const float*)d_in[7];
  const float* bhh1 = (const float*)d_in[8];
  const float* Wfc  = (const float*)d_in[9];
  const float* bfc  = (const float*)d_in[10];
  float* out = (float*)d_out;
  char* ws = (char*)d_ws;

  // zero rings + flags (harness poisons ws with 0xAA before every launch)
  size_t zero_bytes = (size_t)(2048u << 10) + (size_t)4 * N_T * 8 * sizeof(int);
  hipMemsetAsync(d_ws, 0, zero_bytes, stream);

  lstm_kernel<<<dim3(128), dim3(256), 0, stream>>>(
      x, Wxh0, bxh0, Whh0, bhh0, Wxh1, bxh1, Whh1, bhh1, Wfc, bfc, out, ws);
}